// Round 9
// baseline (522.453 us; speedup 1.0000x reference)
//
#include <hip/hip_runtime.h>
#include <hip/hip_bf16.h>
#include <math.h>

#define N_NODES 50000
#define E_EDGES 400000
#define EN_TOT  (E_EDGES + N_NODES)
#define F_IN    128
#define HC      384
#define CLASSES 40

typedef short short8 __attribute__((ext_vector_type(8)));
typedef float floatx4 __attribute__((ext_vector_type(4)));
typedef unsigned int uint;

__device__ __forceinline__ float bf2f(unsigned short u) {
  union { unsigned int i; float f; } x; x.i = ((unsigned int)u) << 16; return x.f;
}
__device__ __forceinline__ unsigned short f2bf(float f) {
  union { float f; unsigned int i; } x; x.f = f;
  unsigned int r = x.i + 0x7fffu + ((x.i >> 16) & 1u);
  return (unsigned short)(r >> 16);
}
__device__ __forceinline__ float fin(float v) {        // NaN/Inf -> 0 (no-op on healthy path)
  return (fabsf(v) < 1e30f) ? v : 0.f;
}
__device__ __forceinline__ float rdw(const void* p, int idx, int fp32) {
  return fp32 ? ((const float*)p)[idx] : bf2f(((const unsigned short*)p)[idx]);
}
// VALU-pipe partial-sum add via DPP (no LDS, no lgkmcnt). CTRL must be an
// immediate: template parameter. 0xB1=quad xor1, 0x4E=quad xor2,
// 0x124=row_ror:4, 0x128=row_ror:8. Chain of 4 = sum over row-of-16.
template <int CTRL>
__device__ __forceinline__ float dpp_radd(float v) {
  union { float f; int i; } u, r;
  u.f = v;
  r.i = __builtin_amdgcn_update_dpp(0, u.i, CTRL, 0xF, 0xF, true);
  return v + r.f;
}

// ---------------- dtype detector (kept: auto-handles bf16-input datasets) ----------
__global__ void k_detect(const unsigned short* __restrict__ x, int* __restrict__ flag) {
  int L = threadIdx.x;
  int sane = 0;
#pragma unroll
  for (int i = 0; i < 4; ++i) {
    unsigned short u = x[(size_t)(L * 4 + i) * 2];
    unsigned int mag = u & 0x7FFFu;
    unsigned int e   = (u >> 7) & 0xFFu;
    if (mag == 0u || (e >= 96u && e <= 159u)) sane++;
  }
  sane += __shfl_xor(sane, 1);
  sane += __shfl_xor(sane, 2);
  sane += __shfl_xor(sane, 4);
  sane += __shfl_xor(sane, 8);
  sane += __shfl_xor(sane, 16);
  sane += __shfl_xor(sane, 32);
  if (L == 0) flag[0] = (sane < 179) ? 1 : 0;   // 1 => inputs are fp32
}

__global__ void k_sentinel(float* out, int n) {
  int i = blockIdx.x * 256 + threadIdx.x;
  if (i < n) out[i] = 111.0f;
}

// ---------------- CSR build ----------------
__global__ void k_zero(int* p, int n) {
  int i = blockIdx.x * 256 + threadIdx.x;
  if (i < n) p[i] = 0;
}

__global__ void k_count(const int* __restrict__ ei, int* __restrict__ counts) {
  int e = blockIdx.x * 256 + threadIdx.x;
  if (e >= EN_TOT) return;
  int dst = (e < E_EDGES) ? ei[E_EDGES + e] : (e - E_EDGES);
  if ((unsigned)dst < N_NODES) atomicAdd(&counts[dst], 1);
}

// hierarchical scan
__global__ void k_scan1(const int* __restrict__ counts, int* __restrict__ row_start,
                        int* __restrict__ bsum) {
  int b = blockIdx.x, tid = threadIdx.x;
  int i = b * 1024 + tid;
  int v = (i < N_NODES) ? counts[i] : 0;
  int lane = tid & 63, w = tid >> 6;
  int x = v;
#pragma unroll
  for (int d = 1; d < 64; d <<= 1) { int t = __shfl_up(x, d); if (lane >= d) x += t; }
  __shared__ int wsum[16];
  if (lane == 63) wsum[w] = x;
  __syncthreads();
  if (w == 0) {
    int y = (lane < 16) ? wsum[lane] : 0;
#pragma unroll
    for (int d = 1; d < 16; d <<= 1) { int t = __shfl_up(y, d); if (lane >= d) y += t; }
    if (lane < 16) wsum[lane] = y;
  }
  __syncthreads();
  if (w > 0) x += wsum[w - 1];
  if (i < N_NODES) row_start[i + 1] = x;
  if (tid == 1023) bsum[b] = x;
}
__global__ void k_scan2(int* bsum, int nb) {
  int lane = threadIdx.x;
  int x = (lane < nb) ? bsum[lane] : 0;
#pragma unroll
  for (int d = 1; d < 64; d <<= 1) { int t = __shfl_up(x, d); if (lane >= d) x += t; }
  if (lane < nb) bsum[lane] = x;
}
__global__ void k_scan3(int* __restrict__ row_start, const int* __restrict__ bsum) {
  int b = blockIdx.x, tid = threadIdx.x;
  int i = b * 1024 + tid;
  if (i >= N_NODES) return;
  int add = (b > 0) ? bsum[b - 1] : 0;
  row_start[i + 1] += add;
  if (i == 0) row_start[0] = 0;
}

__global__ void k_fill(const int* __restrict__ ei, const int* __restrict__ row_start,
                       int* __restrict__ cursor, int* __restrict__ csr_src) {
  int e = blockIdx.x * 256 + threadIdx.x;
  if (e >= EN_TOT) return;
  int src, dst;
  if (e < E_EDGES) { src = ei[e]; dst = ei[E_EDGES + e]; }
  else             { src = dst = e - E_EDGES; }
  if ((unsigned)dst >= N_NODES) return;
  int pos = atomicAdd(&cursor[dst], 1);
  int slot = row_start[dst] + pos;
  if ((unsigned)slot < EN_TOT) csr_src[slot] = src;
}

// ---------------- B packing into MFMA fragment order (N = NT*16 cols) ----------
__global__ void k_pack_b(const void* __restrict__ B, unsigned short* __restrict__ Bp,
                         int K, int NT, const int* __restrict__ flagp) {
  int N = NT * 16;
  int idx = blockIdx.x * 256 + threadIdx.x;
  if (idx >= K * N) return;
  int fp32 = flagp[0];
  int j  = idx & 7;
  int L  = (idx >> 3) & 63;
  int t  = idx >> 9;       // kt*NT + nt
  int nt = t % NT;
  int kt = t / NT;
  int k  = kt * 32 + ((L >> 4) * 8) + j;
  int n  = nt * 16 + (L & 15);
  float v = rdw(B, k * N + n, fp32);
  Bp[idx] = f2bf(fin(v));
}

// ---------------- GEMM: block = 4 waves = 32 rows x 384 cols, LDS-staged B -----
// Wave w: BOTH m-tiles (rows m0..m0+31) x n-tiles [6w, 6w+6): per kt 2 af loads +
// 6 ds_read_b128 feed 12 MFMA (B-frag reuse 2x vs r7's 1x). A/C may alias:
// rows are block-private, and the pre-epilogue __syncthreads orders all A-loads
// before any C-store.
__global__ __launch_bounds__(256) void k_gemm_lds(const void* A_,
                       const unsigned short* __restrict__ Bp,
                       unsigned short* C, int K,
                       const int* __restrict__ flagp, int a_flagged) {
  __shared__ __align__(16) unsigned short Bs[24 * 64 * 8];   // 24 KB
  int fp32 = a_flagged ? flagp[0] : 0;
  int tid  = threadIdx.x;
  int wave = tid >> 6, lane = tid & 63;
  int ntb  = wave * 6;
  int m0   = blockIdx.x * 32;
  int r0   = m0 + (lane & 15);
  int r1   = r0 + 16;
  int r0c  = r0 < N_NODES ? r0 : N_NODES - 1;
  int r1c  = r1 < N_NODES ? r1 : N_NODES - 1;
  int kk   = (lane >> 4) * 8;
  floatx4 acc[12];                       // [mi*6 + nt]
#pragma unroll
  for (int i = 0; i < 12; ++i) acc[i] = (floatx4){0.f, 0.f, 0.f, 0.f};
  int nk = K >> 5;
  const uint4* bsrc = (const uint4*)Bp;
  for (int kt = 0; kt < nk; ++kt) {
    __syncthreads();                      // previous compute done reading Bs
    {
      const uint4* src = bsrc + (size_t)kt * 1536;
      uint4* dst = (uint4*)Bs;
#pragma unroll
      for (int i = 0; i < 6; ++i) dst[tid + 256 * i] = src[tid + 256 * i];
    }
    short8 af0, af1;
    if (fp32) {
      const float* A0 = (const float*)A_ + (size_t)r0c * K + kt * 32 + kk;
      const float* A1 = (const float*)A_ + (size_t)r1c * K + kt * 32 + kk;
      floatx4 f0 = *(const floatx4*)(A0);
      floatx4 f1 = *(const floatx4*)(A0 + 4);
      floatx4 g0 = *(const floatx4*)(A1);
      floatx4 g1 = *(const floatx4*)(A1 + 4);
#pragma unroll
      for (int j = 0; j < 4; ++j) {
        af0[j] = (short)f2bf(f0[j]); af0[4 + j] = (short)f2bf(f1[j]);
        af1[j] = (short)f2bf(g0[j]); af1[4 + j] = (short)f2bf(g1[j]);
      }
    } else {
      af0 = *(const short8*)((const unsigned short*)A_ + (size_t)r0c * K + kt * 32 + kk);
      af1 = *(const short8*)((const unsigned short*)A_ + (size_t)r1c * K + kt * 32 + kk);
    }
    __syncthreads();                      // Bs ready
#pragma unroll
    for (int nt = 0; nt < 6; ++nt) {
      short8 bf = *(const short8*)(Bs + ((size_t)(ntb + nt) * 64 + lane) * 8);
      acc[nt]     = __builtin_amdgcn_mfma_f32_16x16x32_bf16(af0, bf, acc[nt],     0, 0, 0);
      acc[6 + nt] = __builtin_amdgcn_mfma_f32_16x16x32_bf16(af1, bf, acc[6 + nt], 0, 0, 0);
    }
  }
  __syncthreads();                        // all A-loads complete before stores (in-place)
  int qr   = lane >> 4;
  int ccol = lane & 15;
#pragma unroll
  for (int mi = 0; mi < 2; ++mi)
#pragma unroll
    for (int nt = 0; nt < 6; ++nt)
#pragma unroll
      for (int r = 0; r < 4; ++r) {
        int orow = m0 + mi * 16 + qr * 4 + r;
        if (orow < N_NODES)
          C[(size_t)orow * HC + (ntb + nt) * 16 + ccol] = f2bf(fin(acc[mi * 6 + nt][r]));
      }
}

// ---------------- MLP-1 via MFMA: C[M,32] = ELU(A[M,384] @ W3p + b3) ------------
__global__ void k_mlp1_mfma(const unsigned short* __restrict__ H2,
                            const unsigned short* __restrict__ Bp3,
                            const void* __restrict__ b3, float* __restrict__ H3,
                            const int* __restrict__ flagp) {
  int fp32 = flagp[0];
  int lane = threadIdx.x;
  int m0   = blockIdx.x * 16;
  int row  = m0 + (lane & 15);
  int kk   = (lane >> 4) * 8;
  floatx4 acc[2];
  acc[0] = (floatx4){0.f, 0.f, 0.f, 0.f};
  acc[1] = (floatx4){0.f, 0.f, 0.f, 0.f};
#pragma unroll
  for (int kt = 0; kt < 12; ++kt) {
    short8 af = *(const short8*)(H2 + (size_t)row * HC + kt * 32 + kk);
    const short8* bp = (const short8*)Bp3 + (size_t)kt * 2 * 64 + lane;
    acc[0] = __builtin_amdgcn_mfma_f32_16x16x32_bf16(af, bp[0],  acc[0], 0, 0, 0);
    acc[1] = __builtin_amdgcn_mfma_f32_16x16x32_bf16(af, bp[64], acc[1], 0, 0, 0);
  }
  int qr   = lane >> 4;
  int ccol = lane & 15;
#pragma unroll
  for (int nt = 0; nt < 2; ++nt)
#pragma unroll
    for (int r = 0; r < 4; ++r) {
      int col = nt * 16 + ccol;
      float s = acc[nt][r] + fin(rdw(b3, col, fp32));
      s = s > 0.f ? s : expm1f(s);
      H3[(size_t)(m0 + qr * 4 + r) * 32 + col] = fin(s);
    }
}

// ---------------- edge aggregation: wave per dst node, NO-MAX softmax ----------
// 4 nodes per 256-thread block (one per wave). Pair layout: lane L owns channels
// c = 2L + 128k + {0,1}, k=0..2; head(c) = (L>>4) + 4k; head sum = DPP chain
// over the row-of-16 (VALU pipe, no LDS). Clamp +-87 = overflow hard-stop only.
__global__ __launch_bounds__(256) void k_edge(const unsigned short* __restrict__ XL,
                       const unsigned short* XR,
                       const int* __restrict__ row_start, const int* __restrict__ csr_src,
                       const void* __restrict__ att, const void* __restrict__ bias,
                       unsigned short* H, const int* __restrict__ flagp) {
  int fp32 = flagp[0];
  int v = blockIdx.x * 4 + (threadIdx.x >> 6);
  if (v >= N_NODES) return;
  int L = threadIdx.x & 63;
  float r0[3], r1[3], a0[3], a1[3];
  const uint* xr_row = (const uint*)(XR + (size_t)v * HC);
#pragma unroll
  for (int k = 0; k < 3; ++k) {
    uint rv = xr_row[L + 64 * k];
    r0[k] = bf2f((unsigned short)(rv & 0xFFFFu));
    r1[k] = bf2f((unsigned short)(rv >> 16));
    int c = 2 * L + 128 * k;
    a0[k] = fin(rdw(att, c, fp32));
    a1[k] = fin(rdw(att, c + 1, fp32));
  }
  float l[3]    = {0.f, 0.f, 0.f};
  float acc0[3] = {0.f, 0.f, 0.f};
  float acc1[3] = {0.f, 0.f, 0.f};
  int beg = row_start[v], end = row_start[v + 1];
  if (beg < 0) beg = 0;
  if (end > EN_TOT) end = EN_TOT;
  for (int e = beg; e < end; ++e) {
    int s = csr_src[e];
    if ((unsigned)s >= N_NODES) s = 0;
    const uint* xs = (const uint*)(XL + (size_t)s * HC);
    uint q[3];
    q[0] = xs[L];
    q[1] = xs[L + 64];
    q[2] = xs[L + 128];
#pragma unroll
    for (int k = 0; k < 3; ++k) {
      float s0 = bf2f((unsigned short)(q[k] & 0xFFFFu));
      float s1 = bf2f((unsigned short)(q[k] >> 16));
      float t0 = s0 + r0[k]; t0 = fmaxf(t0, 0.2f * t0);   // leaky_relu(t,0.2)
      float t1 = s1 + r1[k]; t1 = fmaxf(t1, 0.2f * t1);
      float w = t0 * a0[k] + t1 * a1[k];
      w = dpp_radd<0xB1>(w);               // quad xor1
      w = dpp_radd<0x4E>(w);               // quad xor2
      w = dpp_radd<0x124>(w);              // row_ror:4
      w = dpp_radd<0x128>(w);              // row_ror:8 -> sum over 16-lane head group
      w = fminf(fmaxf(w, -87.f), 87.f);    // overflow hard-stop only
      float p = __expf(w);
      l[k] += p;
      acc0[k] = fmaf(p, s0, acc0[k]);
      acc1[k] = fmaf(p, s1, acc1[k]);
    }
  }
  uint* hr = (uint*)(H + (size_t)v * HC);
#pragma unroll
  for (int k = 0; k < 3; ++k) {
    int c = 2 * L + 128 * k;
    float inv = 1.f / fmaxf(l[k], 1e-30f);
    float o0 = acc0[k] * inv + fin(rdw(bias, c, fp32));
    float o1 = acc1[k] * inv + fin(rdw(bias, c + 1, fp32));
    o0 = o0 > 0.f ? o0 : expm1f(o0);
    o1 = o1 > 0.f ? o1 : expm1f(o1);
    hr[L + 64 * k] = (uint)f2bf(fin(o0)) | ((uint)f2bf(fin(o1)) << 16);
  }
}

// ---------------- MLP-2 + log_softmax ----------------
__global__ void k_mlp2(const float* __restrict__ H3, const void* __restrict__ W4,
                       const void* __restrict__ b4, float* __restrict__ out,
                       const int* __restrict__ flagp) {
  int fp32 = flagp[0];
  int v = blockIdx.x;
  int L = threadIdx.x;
  float logit = -1e30f;
  if (L < CLASSES) {
    logit = rdw(b4, L, fp32);
#pragma unroll
    for (int k = 0; k < 32; ++k)
      logit += H3[(size_t)v * 32 + k] * rdw(W4, k * CLASSES + L, fp32);
  }
  float mx = logit;
  for (int off = 1; off < 64; off <<= 1) mx = fmaxf(mx, __shfl_xor(mx, off));
  float ex = (L < CLASSES) ? __expf(logit - mx) : 0.f;
  ex = (ex == ex) ? ex : 0.f;
  float sm = ex;
  for (int off = 1; off < 64; off <<= 1) sm += __shfl_xor(sm, off);
  float ls = mx + logf(sm);
  if (L < CLASSES) out[(size_t)v * CLASSES + L] = fin(logit - ls);
}

extern "C" void kernel_launch(void* const* d_in, const int* in_sizes, int n_in,
                              void* d_out, int out_size, void* d_ws, size_t ws_size,
                              hipStream_t stream) {
  const void* x   = d_in[0];
  const int* ei   = (const int*)d_in[1];
  const void* Wl1 = d_in[2];
  const void* Wr1 = d_in[3];
  const void* a1  = d_in[4];
  const void* b1  = d_in[5];
  const void* Wl2 = d_in[6];
  const void* Wr2 = d_in[7];
  const void* a2  = d_in[8];
  const void* b2  = d_in[9];
  const void* W3  = d_in[10];
  const void* b3  = d_in[11];
  const void* W4  = d_in[12];
  const void* b4  = d_in[13];
  float* out = (float*)d_out;

  char* ws = (char*)d_ws;
  size_t off = 0;
  auto alloc = [&](size_t bytes) { size_t o = off; off += (bytes + 255) & ~(size_t)255; return o; };
  int* flag       = (int*)(ws + alloc(256));
  int* row_start  = (int*)(ws + alloc((size_t)(N_NODES + 1) * 4));
  int* counts     = (int*)(ws + alloc((size_t)N_NODES * 4));
  int* cursor     = (int*)(ws + alloc((size_t)N_NODES * 4));
  int* bsum       = (int*)(ws + alloc(64 * 4));
  int* csr_src    = (int*)(ws + alloc((size_t)EN_TOT * 4));
  unsigned short* Bp  = (unsigned short*)(ws + alloc((size_t)HC * HC * 2));
  unsigned short* Bp3 = (unsigned short*)(ws + alloc((size_t)HC * 32 * 2));   // 24 KB
  unsigned short* B0  = (unsigned short*)(ws + alloc((size_t)N_NODES * HC * 2));
  unsigned short* B1  = (unsigned short*)(ws + alloc((size_t)N_NODES * HC * 2));
  float* H3       = (float*)B0;  // reuses B0 after it's dead
  (void)in_sizes; (void)n_in;

  if (ws_size < off) {
    k_sentinel<<<(out_size + 255) / 256, 256, 0, stream>>>(out, out_size);
    return;
  }

  const int SCAN_BLOCKS = (N_NODES + 1023) / 1024;   // 49
  const int GEMM_BLOCKS = (N_NODES + 31) / 32;       // 1563
  const int EDGE_BLOCKS = (N_NODES + 3) / 4;         // 12500

  k_detect<<<1, 64, 0, stream>>>((const unsigned short*)x, flag);

  // --- CSR by dst ---
  k_zero<<<(N_NODES + 255) / 256, 256, 0, stream>>>(counts, N_NODES);
  k_zero<<<(N_NODES + 255) / 256, 256, 0, stream>>>(cursor, N_NODES);
  k_count<<<(EN_TOT + 255) / 256, 256, 0, stream>>>(ei, counts);
  k_scan1<<<SCAN_BLOCKS, 1024, 0, stream>>>(counts, row_start, bsum);
  k_scan2<<<1, 64, 0, stream>>>(bsum, SCAN_BLOCKS);
  k_scan3<<<SCAN_BLOCKS, 1024, 0, stream>>>(row_start, bsum);
  k_fill<<<(EN_TOT + 255) / 256, 256, 0, stream>>>(ei, row_start, cursor, csr_src);

  // --- layer 1 ---
  k_pack_b<<<(F_IN * HC + 255) / 256, 256, 0, stream>>>(Wl1, Bp, F_IN, 24, flag);
  k_gemm_lds<<<GEMM_BLOCKS, 256, 0, stream>>>(x, Bp, B0, F_IN, flag, 1);
  k_pack_b<<<(F_IN * HC + 255) / 256, 256, 0, stream>>>(Wr1, Bp, F_IN, 24, flag);
  k_gemm_lds<<<GEMM_BLOCKS, 256, 0, stream>>>(x, Bp, B1, F_IN, flag, 1);
  k_edge<<<EDGE_BLOCKS, 256, 0, stream>>>(B0, B1, row_start, csr_src, a1, b1, B1, flag);

  // --- layer 2 ---
  k_pack_b<<<(HC * HC + 255) / 256, 256, 0, stream>>>(Wl2, Bp, HC, 24, flag);
  k_gemm_lds<<<GEMM_BLOCKS, 256, 0, stream>>>(B1, Bp, B0, HC, flag, 0);
  k_pack_b<<<(HC * HC + 255) / 256, 256, 0, stream>>>(Wr2, Bp, HC, 24, flag);
  k_gemm_lds<<<GEMM_BLOCKS, 256, 0, stream>>>(B1, Bp, B1, HC, flag, 0);
  k_edge<<<EDGE_BLOCKS, 256, 0, stream>>>(B0, B1, row_start, csr_src, a2, b2, B1, flag);

  // --- MLP head + log_softmax ---
  k_pack_b<<<(HC * 32 + 255) / 256, 256, 0, stream>>>(W3, Bp3, HC, 2, flag);
  k_mlp1_mfma<<<N_NODES / 16, 64, 0, stream>>>(B1, Bp3, b3, H3, flag);
  k_mlp2<<<N_NODES, 64, 0, stream>>>(H3, W4, b4, out, flag);
}

// Round 10
// 480.507 us; speedup vs baseline: 1.0873x; 1.0873x over previous
//
#include <hip/hip_runtime.h>
#include <hip/hip_bf16.h>
#include <math.h>

#define N_NODES 50000
#define E_EDGES 400000
#define EN_TOT  (E_EDGES + N_NODES)
#define F_IN    128
#define HC      384
#define CLASSES 40

typedef short short8 __attribute__((ext_vector_type(8)));
typedef float floatx4 __attribute__((ext_vector_type(4)));
typedef unsigned int uint;

__device__ __forceinline__ float bf2f(unsigned short u) {
  union { unsigned int i; float f; } x; x.i = ((unsigned int)u) << 16; return x.f;
}
__device__ __forceinline__ unsigned short f2bf(float f) {
  union { float f; unsigned int i; } x; x.f = f;
  unsigned int r = x.i + 0x7fffu + ((x.i >> 16) & 1u);
  return (unsigned short)(r >> 16);
}
__device__ __forceinline__ float fin(float v) {        // NaN/Inf -> 0 (no-op on healthy path)
  return (fabsf(v) < 1e30f) ? v : 0.f;
}
__device__ __forceinline__ float rdw(const void* p, int idx, int fp32) {
  return fp32 ? ((const float*)p)[idx] : bf2f(((const unsigned short*)p)[idx]);
}

// ---------------- dtype detector (kept: auto-handles bf16-input datasets) ----------
__global__ void k_detect(const unsigned short* __restrict__ x, int* __restrict__ flag) {
  int L = threadIdx.x;
  int sane = 0;
#pragma unroll
  for (int i = 0; i < 4; ++i) {
    unsigned short u = x[(size_t)(L * 4 + i) * 2];
    unsigned int mag = u & 0x7FFFu;
    unsigned int e   = (u >> 7) & 0xFFu;
    if (mag == 0u || (e >= 96u && e <= 159u)) sane++;
  }
  sane += __shfl_xor(sane, 1);
  sane += __shfl_xor(sane, 2);
  sane += __shfl_xor(sane, 4);
  sane += __shfl_xor(sane, 8);
  sane += __shfl_xor(sane, 16);
  sane += __shfl_xor(sane, 32);
  if (L == 0) flag[0] = (sane < 179) ? 1 : 0;   // 1 => inputs are fp32
}

__global__ void k_sentinel(float* out, int n) {
  int i = blockIdx.x * 256 + threadIdx.x;
  if (i < n) out[i] = 111.0f;
}

// ---------------- CSR build ----------------
__global__ void k_zero(int* p, int n) {
  int i = blockIdx.x * 256 + threadIdx.x;
  if (i < n) p[i] = 0;
}

__global__ void k_count(const int* __restrict__ ei, int* __restrict__ counts) {
  int e = blockIdx.x * 256 + threadIdx.x;
  if (e >= EN_TOT) return;
  int dst = (e < E_EDGES) ? ei[E_EDGES + e] : (e - E_EDGES);
  if ((unsigned)dst < N_NODES) atomicAdd(&counts[dst], 1);
}

// hierarchical scan
__global__ void k_scan1(const int* __restrict__ counts, int* __restrict__ row_start,
                        int* __restrict__ bsum) {
  int b = blockIdx.x, tid = threadIdx.x;
  int i = b * 1024 + tid;
  int v = (i < N_NODES) ? counts[i] : 0;
  int lane = tid & 63, w = tid >> 6;
  int x = v;
#pragma unroll
  for (int d = 1; d < 64; d <<= 1) { int t = __shfl_up(x, d); if (lane >= d) x += t; }
  __shared__ int wsum[16];
  if (lane == 63) wsum[w] = x;
  __syncthreads();
  if (w == 0) {
    int y = (lane < 16) ? wsum[lane] : 0;
#pragma unroll
    for (int d = 1; d < 16; d <<= 1) { int t = __shfl_up(y, d); if (lane >= d) y += t; }
    if (lane < 16) wsum[lane] = y;
  }
  __syncthreads();
  if (w > 0) x += wsum[w - 1];
  if (i < N_NODES) row_start[i + 1] = x;
  if (tid == 1023) bsum[b] = x;
}
__global__ void k_scan2(int* bsum, int nb) {
  int lane = threadIdx.x;
  int x = (lane < nb) ? bsum[lane] : 0;
#pragma unroll
  for (int d = 1; d < 64; d <<= 1) { int t = __shfl_up(x, d); if (lane >= d) x += t; }
  if (lane < nb) bsum[lane] = x;
}
__global__ void k_scan3(int* __restrict__ row_start, const int* __restrict__ bsum) {
  int b = blockIdx.x, tid = threadIdx.x;
  int i = b * 1024 + tid;
  if (i >= N_NODES) return;
  int add = (b > 0) ? bsum[b - 1] : 0;
  row_start[i + 1] += add;
  if (i == 0) row_start[0] = 0;
}

__global__ void k_fill(const int* __restrict__ ei, const int* __restrict__ row_start,
                       int* __restrict__ cursor, int* __restrict__ csr_src) {
  int e = blockIdx.x * 256 + threadIdx.x;
  if (e >= EN_TOT) return;
  int src, dst;
  if (e < E_EDGES) { src = ei[e]; dst = ei[E_EDGES + e]; }
  else             { src = dst = e - E_EDGES; }
  if ((unsigned)dst >= N_NODES) return;
  int pos = atomicAdd(&cursor[dst], 1);
  int slot = row_start[dst] + pos;
  if ((unsigned)slot < EN_TOT) csr_src[slot] = src;
}

// ---------------- B packing into MFMA fragment order (N = NT*16 cols) ----------
__global__ void k_pack_b(const void* __restrict__ B, unsigned short* __restrict__ Bp,
                         int K, int NT, const int* __restrict__ flagp) {
  int N = NT * 16;
  int idx = blockIdx.x * 256 + threadIdx.x;
  if (idx >= K * N) return;
  int fp32 = flagp[0];
  int j  = idx & 7;
  int L  = (idx >> 3) & 63;
  int t  = idx >> 9;       // kt*NT + nt
  int nt = t % NT;
  int kt = t / NT;
  int k  = kt * 32 + ((L >> 4) * 8) + j;
  int n  = nt * 16 + (L & 15);
  float v = rdw(B, k * N + n, fp32);
  Bp[idx] = f2bf(fin(v));
}

// ---------------- GEMM: barrier-free. Block = 4 waves x (4 m-tiles x 6 nt) ------
// Block covers rows [64b, 64b+64) x all 384 cols. Wave w owns n-tiles
// [6w, 6w+6) for ALL 4 m-tiles: per kt, 4 af loads + 6 B-frag loads (straight
// from L2 -- each frag fetched by exactly one wave; no LDS, no k-loop barriers,
// so waves software-pipeline loads across kt freely). acc = 24 x float4.
// In-place safe (C may alias A): blocks are row-disjoint; within the block the
// single pre-epilogue __syncthreads orders all A-reads before any C-store.
__global__ __launch_bounds__(256) void k_gemm4(const void* A_,
                       const unsigned short* __restrict__ Bp,
                       unsigned short* C, int K,
                       const int* __restrict__ flagp, int a_flagged) {
  int fp32 = a_flagged ? flagp[0] : 0;
  int tid  = threadIdx.x;
  int wave = tid >> 6, lane = tid & 63;
  int ntb  = wave * 6;
  int m0   = blockIdx.x * 64;
  int lr   = lane & 15;
  int kk   = (lane >> 4) * 8;
  int rc[4];
#pragma unroll
  for (int mi = 0; mi < 4; ++mi) {
    int r = m0 + mi * 16 + lr;
    rc[mi] = r < N_NODES ? r : N_NODES - 1;
  }
  floatx4 acc[24];                       // [mi*6 + nt]
#pragma unroll
  for (int i = 0; i < 24; ++i) acc[i] = (floatx4){0.f, 0.f, 0.f, 0.f};
  int nk = K >> 5;
  for (int kt = 0; kt < nk; ++kt) {
    short8 af[4];
    if (fp32) {
#pragma unroll
      for (int mi = 0; mi < 4; ++mi) {
        const float* Af = (const float*)A_ + (size_t)rc[mi] * K + kt * 32 + kk;
        floatx4 f0 = *(const floatx4*)(Af);
        floatx4 f1 = *(const floatx4*)(Af + 4);
#pragma unroll
        for (int j = 0; j < 4; ++j) { af[mi][j] = (short)f2bf(f0[j]); af[mi][4 + j] = (short)f2bf(f1[j]); }
      }
    } else {
#pragma unroll
      for (int mi = 0; mi < 4; ++mi)
        af[mi] = *(const short8*)((const unsigned short*)A_ + (size_t)rc[mi] * K + kt * 32 + kk);
    }
    const short8* bp = (const short8*)Bp + ((size_t)kt * 24 + ntb) * 64 + lane;
#pragma unroll
    for (int nt = 0; nt < 6; ++nt) {
      short8 bf = bp[nt * 64];
      acc[0 * 6 + nt] = __builtin_amdgcn_mfma_f32_16x16x32_bf16(af[0], bf, acc[0 * 6 + nt], 0, 0, 0);
      acc[1 * 6 + nt] = __builtin_amdgcn_mfma_f32_16x16x32_bf16(af[1], bf, acc[1 * 6 + nt], 0, 0, 0);
      acc[2 * 6 + nt] = __builtin_amdgcn_mfma_f32_16x16x32_bf16(af[2], bf, acc[2 * 6 + nt], 0, 0, 0);
      acc[3 * 6 + nt] = __builtin_amdgcn_mfma_f32_16x16x32_bf16(af[3], bf, acc[3 * 6 + nt], 0, 0, 0);
    }
  }
  __syncthreads();                        // all A-loads complete before stores (in-place)
  int qr   = lane >> 4;
  int ccol = lane & 15;
#pragma unroll
  for (int mi = 0; mi < 4; ++mi)
#pragma unroll
    for (int nt = 0; nt < 6; ++nt)
#pragma unroll
      for (int r = 0; r < 4; ++r) {
        int orow = m0 + mi * 16 + qr * 4 + r;
        if (orow < N_NODES)
          C[(size_t)orow * HC + (ntb + nt) * 16 + ccol] = f2bf(fin(acc[mi * 6 + nt][r]));
      }
}

// ---------------- MLP-1 via MFMA: C[M,32] = ELU(A[M,384] @ W3p + b3) ------------
__global__ void k_mlp1_mfma(const unsigned short* __restrict__ H2,
                            const unsigned short* __restrict__ Bp3,
                            const void* __restrict__ b3, float* __restrict__ H3,
                            const int* __restrict__ flagp) {
  int fp32 = flagp[0];
  int lane = threadIdx.x;
  int m0   = blockIdx.x * 16;
  int row  = m0 + (lane & 15);
  int kk   = (lane >> 4) * 8;
  floatx4 acc[2];
  acc[0] = (floatx4){0.f, 0.f, 0.f, 0.f};
  acc[1] = (floatx4){0.f, 0.f, 0.f, 0.f};
#pragma unroll
  for (int kt = 0; kt < 12; ++kt) {
    short8 af = *(const short8*)(H2 + (size_t)row * HC + kt * 32 + kk);
    const short8* bp = (const short8*)Bp3 + (size_t)kt * 2 * 64 + lane;
    acc[0] = __builtin_amdgcn_mfma_f32_16x16x32_bf16(af, bp[0],  acc[0], 0, 0, 0);
    acc[1] = __builtin_amdgcn_mfma_f32_16x16x32_bf16(af, bp[64], acc[1], 0, 0, 0);
  }
  int qr   = lane >> 4;
  int ccol = lane & 15;
#pragma unroll
  for (int nt = 0; nt < 2; ++nt)
#pragma unroll
    for (int r = 0; r < 4; ++r) {
      int col = nt * 16 + ccol;
      float s = acc[nt][r] + fin(rdw(b3, col, fp32));
      s = s > 0.f ? s : expm1f(s);
      H3[(size_t)(m0 + qr * 4 + r) * 32 + col] = fin(s);
    }
}

// ---------------- edge aggregation (r7 proven): wave per dst node --------------
// NO-MAX softmax (shift-invariance; logits O(+-12); clamp +-87 = overflow stop).
// Pair layout: lane L owns channels c = 2L + 128k + {0,1}, k=0..2;
// head(c) = (L>>4) + 4k -> 16-lane reduction groups via DS-pipe shuffles
// (co-issue with other waves' VALU -- measured better than VALU DPP chain).
__global__ void k_edge(const unsigned short* __restrict__ XL, const unsigned short* XR,
                       const int* __restrict__ row_start, const int* __restrict__ csr_src,
                       const void* __restrict__ att, const void* __restrict__ bias,
                       unsigned short* H, const int* __restrict__ flagp) {
  int fp32 = flagp[0];
  int v = blockIdx.x;
  int L = threadIdx.x;
  float r0[3], r1[3], a0[3], a1[3];
  const uint* xr_row = (const uint*)(XR + (size_t)v * HC);
#pragma unroll
  for (int k = 0; k < 3; ++k) {
    uint rv = xr_row[L + 64 * k];
    r0[k] = bf2f((unsigned short)(rv & 0xFFFFu));
    r1[k] = bf2f((unsigned short)(rv >> 16));
    int c = 2 * L + 128 * k;
    a0[k] = fin(rdw(att, c, fp32));
    a1[k] = fin(rdw(att, c + 1, fp32));
  }
  float l[3]    = {0.f, 0.f, 0.f};
  float acc0[3] = {0.f, 0.f, 0.f};
  float acc1[3] = {0.f, 0.f, 0.f};
  int beg = row_start[v], end = row_start[v + 1];
  if (beg < 0) beg = 0;
  if (end > EN_TOT) end = EN_TOT;
  for (int e = beg; e < end; ++e) {
    int s = csr_src[e];
    if ((unsigned)s >= N_NODES) s = 0;
    const uint* xs = (const uint*)(XL + (size_t)s * HC);
    uint q[3];
    q[0] = xs[L];
    q[1] = xs[L + 64];
    q[2] = xs[L + 128];
#pragma unroll
    for (int k = 0; k < 3; ++k) {
      float s0 = bf2f((unsigned short)(q[k] & 0xFFFFu));
      float s1 = bf2f((unsigned short)(q[k] >> 16));
      float t0 = s0 + r0[k]; t0 = fmaxf(t0, 0.2f * t0);   // leaky_relu(t,0.2)
      float t1 = s1 + r1[k]; t1 = fmaxf(t1, 0.2f * t1);
      float w = t0 * a0[k] + t1 * a1[k];
      w += __shfl_xor(w, 1);
      w += __shfl_xor(w, 2);
      w += __shfl_xor(w, 4);
      w += __shfl_xor(w, 8);               // head logit, uniform in 16-lane group
      w = fminf(fmaxf(w, -87.f), 87.f);    // overflow hard-stop only
      float p = __expf(w);
      l[k] += p;
      acc0[k] = fmaf(p, s0, acc0[k]);
      acc1[k] = fmaf(p, s1, acc1[k]);
    }
  }
  uint* hr = (uint*)(H + (size_t)v * HC);
#pragma unroll
  for (int k = 0; k < 3; ++k) {
    int c = 2 * L + 128 * k;
    float inv = 1.f / fmaxf(l[k], 1e-30f);
    float o0 = acc0[k] * inv + fin(rdw(bias, c, fp32));
    float o1 = acc1[k] * inv + fin(rdw(bias, c + 1, fp32));
    o0 = o0 > 0.f ? o0 : expm1f(o0);
    o1 = o1 > 0.f ? o1 : expm1f(o1);
    hr[L + 64 * k] = (uint)f2bf(fin(o0)) | ((uint)f2bf(fin(o1)) << 16);
  }
}

// ---------------- MLP-2 + log_softmax ----------------
__global__ void k_mlp2(const float* __restrict__ H3, const void* __restrict__ W4,
                       const void* __restrict__ b4, float* __restrict__ out,
                       const int* __restrict__ flagp) {
  int fp32 = flagp[0];
  int v = blockIdx.x;
  int L = threadIdx.x;
  float logit = -1e30f;
  if (L < CLASSES) {
    logit = rdw(b4, L, fp32);
#pragma unroll
    for (int k = 0; k < 32; ++k)
      logit += H3[(size_t)v * 32 + k] * rdw(W4, k * CLASSES + L, fp32);
  }
  float mx = logit;
  for (int off = 1; off < 64; off <<= 1) mx = fmaxf(mx, __shfl_xor(mx, off));
  float ex = (L < CLASSES) ? __expf(logit - mx) : 0.f;
  ex = (ex == ex) ? ex : 0.f;
  float sm = ex;
  for (int off = 1; off < 64; off <<= 1) sm += __shfl_xor(sm, off);
  float ls = mx + logf(sm);
  if (L < CLASSES) out[(size_t)v * CLASSES + L] = fin(logit - ls);
}

extern "C" void kernel_launch(void* const* d_in, const int* in_sizes, int n_in,
                              void* d_out, int out_size, void* d_ws, size_t ws_size,
                              hipStream_t stream) {
  const void* x   = d_in[0];
  const int* ei   = (const int*)d_in[1];
  const void* Wl1 = d_in[2];
  const void* Wr1 = d_in[3];
  const void* a1  = d_in[4];
  const void* b1  = d_in[5];
  const void* Wl2 = d_in[6];
  const void* Wr2 = d_in[7];
  const void* a2  = d_in[8];
  const void* b2  = d_in[9];
  const void* W3  = d_in[10];
  const void* b3  = d_in[11];
  const void* W4  = d_in[12];
  const void* b4  = d_in[13];
  float* out = (float*)d_out;

  char* ws = (char*)d_ws;
  size_t off = 0;
  auto alloc = [&](size_t bytes) { size_t o = off; off += (bytes + 255) & ~(size_t)255; return o; };
  int* flag       = (int*)(ws + alloc(256));
  int* row_start  = (int*)(ws + alloc((size_t)(N_NODES + 1) * 4));
  int* counts     = (int*)(ws + alloc((size_t)N_NODES * 4));
  int* cursor     = (int*)(ws + alloc((size_t)N_NODES * 4));
  int* bsum       = (int*)(ws + alloc(64 * 4));
  int* csr_src    = (int*)(ws + alloc((size_t)EN_TOT * 4));
  unsigned short* Bp  = (unsigned short*)(ws + alloc((size_t)HC * HC * 2));
  unsigned short* Bp3 = (unsigned short*)(ws + alloc((size_t)HC * 32 * 2));   // 24 KB
  unsigned short* B0  = (unsigned short*)(ws + alloc((size_t)N_NODES * HC * 2));
  unsigned short* B1  = (unsigned short*)(ws + alloc((size_t)N_NODES * HC * 2));
  float* H3       = (float*)B0;  // reuses B0 after it's dead
  (void)in_sizes; (void)n_in;

  if (ws_size < off) {
    k_sentinel<<<(out_size + 255) / 256, 256, 0, stream>>>(out, out_size);
    return;
  }

  const int SCAN_BLOCKS = (N_NODES + 1023) / 1024;   // 49
  const int GEMM_BLOCKS = (N_NODES + 63) / 64;       // 782

  k_detect<<<1, 64, 0, stream>>>((const unsigned short*)x, flag);

  // --- CSR by dst ---
  k_zero<<<(N_NODES + 255) / 256, 256, 0, stream>>>(counts, N_NODES);
  k_zero<<<(N_NODES + 255) / 256, 256, 0, stream>>>(cursor, N_NODES);
  k_count<<<(EN_TOT + 255) / 256, 256, 0, stream>>>(ei, counts);
  k_scan1<<<SCAN_BLOCKS, 1024, 0, stream>>>(counts, row_start, bsum);
  k_scan2<<<1, 64, 0, stream>>>(bsum, SCAN_BLOCKS);
  k_scan3<<<SCAN_BLOCKS, 1024, 0, stream>>>(row_start, bsum);
  k_fill<<<(EN_TOT + 255) / 256, 256, 0, stream>>>(ei, row_start, cursor, csr_src);

  // --- layer 1 ---
  k_pack_b<<<(F_IN * HC + 255) / 256, 256, 0, stream>>>(Wl1, Bp, F_IN, 24, flag);
  k_gemm4<<<GEMM_BLOCKS, 256, 0, stream>>>(x, Bp, B0, F_IN, flag, 1);
  k_pack_b<<<(F_IN * HC + 255) / 256, 256, 0, stream>>>(Wr1, Bp, F_IN, 24, flag);
  k_gemm4<<<GEMM_BLOCKS, 256, 0, stream>>>(x, Bp, B1, F_IN, flag, 1);
  k_edge<<<N_NODES, 64, 0, stream>>>(B0, B1, row_start, csr_src, a1, b1, B1, flag);

  // --- layer 2 ---
  k_pack_b<<<(HC * HC + 255) / 256, 256, 0, stream>>>(Wl2, Bp, HC, 24, flag);
  k_gemm4<<<GEMM_BLOCKS, 256, 0, stream>>>(B1, Bp, B0, HC, flag, 0);
  k_pack_b<<<(HC * HC + 255) / 256, 256, 0, stream>>>(Wr2, Bp, HC, 24, flag);
  k_gemm4<<<GEMM_BLOCKS, 256, 0, stream>>>(B1, Bp, B1, HC, flag, 0);   // in-place, row-disjoint blocks
  k_edge<<<N_NODES, 64, 0, stream>>>(B0, B1, row_start, csr_src, a2, b2, B1, flag);

  // --- MLP head + log_softmax ---
  k_pack_b<<<(HC * 32 + 255) / 256, 256, 0, stream>>>(W3, Bp3, HC, 2, flag);
  k_mlp1_mfma<<<N_NODES / 16, 64, 0, stream>>>(B1, Bp3, b3, H3, flag);
  k_mlp2<<<N_NODES, 64, 0, stream>>>(H3, W4, b4, out, flag);
}

// Round 11
// 476.683 us; speedup vs baseline: 1.0960x; 1.0080x over previous
//
#include <hip/hip_runtime.h>
#include <hip/hip_bf16.h>
#include <math.h>

#define N_NODES 50000
#define E_EDGES 400000
#define EN_TOT  (E_EDGES + N_NODES)
#define F_IN    128
#define HC      384
#define CLASSES 40

typedef short short8 __attribute__((ext_vector_type(8)));
typedef float floatx4 __attribute__((ext_vector_type(4)));
typedef unsigned int uint;

__device__ __forceinline__ float bf2f(unsigned short u) {
  union { unsigned int i; float f; } x; x.i = ((unsigned int)u) << 16; return x.f;
}
__device__ __forceinline__ unsigned short f2bf(float f) {
  union { float f; unsigned int i; } x; x.f = f;
  unsigned int r = x.i + 0x7fffu + ((x.i >> 16) & 1u);
  return (unsigned short)(r >> 16);
}
__device__ __forceinline__ float fin(float v) {        // NaN/Inf -> 0 (no-op on healthy path)
  return (fabsf(v) < 1e30f) ? v : 0.f;
}
__device__ __forceinline__ float rdw(const void* p, int idx, int fp32) {
  return fp32 ? ((const float*)p)[idx] : bf2f(((const unsigned short*)p)[idx]);
}

// ---------------- dtype detector (kept: auto-handles bf16-input datasets) ----------
__global__ void k_detect(const unsigned short* __restrict__ x, int* __restrict__ flag) {
  int L = threadIdx.x;
  int sane = 0;
#pragma unroll
  for (int i = 0; i < 4; ++i) {
    unsigned short u = x[(size_t)(L * 4 + i) * 2];
    unsigned int mag = u & 0x7FFFu;
    unsigned int e   = (u >> 7) & 0xFFu;
    if (mag == 0u || (e >= 96u && e <= 159u)) sane++;
  }
  sane += __shfl_xor(sane, 1);
  sane += __shfl_xor(sane, 2);
  sane += __shfl_xor(sane, 4);
  sane += __shfl_xor(sane, 8);
  sane += __shfl_xor(sane, 16);
  sane += __shfl_xor(sane, 32);
  if (L == 0) flag[0] = (sane < 179) ? 1 : 0;   // 1 => inputs are fp32
}

__global__ void k_sentinel(float* out, int n) {
  int i = blockIdx.x * 256 + threadIdx.x;
  if (i < n) out[i] = 111.0f;
}

// ---------------- CSR build ----------------
__global__ void k_zero2(int* p, int n) {           // zeros counts+cursor in one launch
  int i = blockIdx.x * 256 + threadIdx.x;
  if (i < n) p[i] = 0;
}

__global__ void k_count(const int* __restrict__ ei, int* __restrict__ counts) {
  int e = blockIdx.x * 256 + threadIdx.x;
  if (e >= EN_TOT) return;
  int dst = (e < E_EDGES) ? ei[E_EDGES + e] : (e - E_EDGES);
  if ((unsigned)dst < N_NODES) atomicAdd(&counts[dst], 1);
}

__global__ void k_scan1(const int* __restrict__ counts, int* __restrict__ row_start,
                        int* __restrict__ bsum) {
  int b = blockIdx.x, tid = threadIdx.x;
  int i = b * 1024 + tid;
  int v = (i < N_NODES) ? counts[i] : 0;
  int lane = tid & 63, w = tid >> 6;
  int x = v;
#pragma unroll
  for (int d = 1; d < 64; d <<= 1) { int t = __shfl_up(x, d); if (lane >= d) x += t; }
  __shared__ int wsum[16];
  if (lane == 63) wsum[w] = x;
  __syncthreads();
  if (w == 0) {
    int y = (lane < 16) ? wsum[lane] : 0;
#pragma unroll
    for (int d = 1; d < 16; d <<= 1) { int t = __shfl_up(y, d); if (lane >= d) y += t; }
    if (lane < 16) wsum[lane] = y;
  }
  __syncthreads();
  if (w > 0) x += wsum[w - 1];
  if (i < N_NODES) row_start[i + 1] = x;
  if (tid == 1023) bsum[b] = x;
}
__global__ void k_scan2(int* bsum, int nb) {
  int lane = threadIdx.x;
  int x = (lane < nb) ? bsum[lane] : 0;
#pragma unroll
  for (int d = 1; d < 64; d <<= 1) { int t = __shfl_up(x, d); if (lane >= d) x += t; }
  if (lane < nb) bsum[lane] = x;
}
__global__ void k_scan3(int* __restrict__ row_start, const int* __restrict__ bsum) {
  int b = blockIdx.x, tid = threadIdx.x;
  int i = b * 1024 + tid;
  if (i >= N_NODES) return;
  int add = (b > 0) ? bsum[b - 1] : 0;
  row_start[i + 1] += add;
  if (i == 0) row_start[0] = 0;
}

__global__ void k_fill(const int* __restrict__ ei, const int* __restrict__ row_start,
                       int* __restrict__ cursor, int* __restrict__ csr_src) {
  int e = blockIdx.x * 256 + threadIdx.x;
  if (e >= EN_TOT) return;
  int src, dst;
  if (e < E_EDGES) { src = ei[e]; dst = ei[E_EDGES + e]; }
  else             { src = dst = e - E_EDGES; }
  if ((unsigned)dst >= N_NODES) return;
  int pos = atomicAdd(&cursor[dst], 1);
  int slot = row_start[dst] + pos;
  if ((unsigned)slot < EN_TOT) csr_src[slot] = src;
}

// ---------------- pack ALL weights into MFMA fragment order, one launch ---------
// Bp[((kt*NT+nt)*64+L)*8+j] = B[(kt*32+(L>>4)*8+j)*N + nt*16+(L&15)]
__device__ __forceinline__ void pack_one(const void* B, unsigned short* Bp,
                                         int NT, int idx, int fp32) {
  int N = NT * 16;
  int j  = idx & 7;
  int L  = (idx >> 3) & 63;
  int t  = idx >> 9;
  int nt = t % NT;
  int kt = t / NT;
  int k  = kt * 32 + ((L >> 4) * 8) + j;
  int n  = nt * 16 + (L & 15);
  Bp[idx] = f2bf(fin(rdw(B, k * N + n, fp32)));
}
#define SZ1 (F_IN * HC)     // 49152
#define SZ2 (HC * HC)       // 147456
#define SZ3 (HC * 32)       // 12288
#define SZALL (2 * SZ1 + 2 * SZ2 + SZ3)
__global__ void k_pack_all(const void* Wl1, const void* Wr1, const void* Wl2,
                           const void* Wr2, const void* W3,
                           unsigned short* Bp1l, unsigned short* Bp1r,
                           unsigned short* Bp2l, unsigned short* Bp2r,
                           unsigned short* Bp3, const int* __restrict__ flagp) {
  int idx = blockIdx.x * 256 + threadIdx.x;
  if (idx >= SZALL) return;
  int fp32 = flagp[0];
  if (idx < SZ1)                { pack_one(Wl1, Bp1l, 24, idx, fp32); return; }
  idx -= SZ1;
  if (idx < SZ1)                { pack_one(Wr1, Bp1r, 24, idx, fp32); return; }
  idx -= SZ1;
  if (idx < SZ2)                { pack_one(Wl2, Bp2l, 24, idx, fp32); return; }
  idx -= SZ2;
  if (idx < SZ2)                { pack_one(Wr2, Bp2r, 24, idx, fp32); return; }
  idx -= SZ2;
  pack_one(W3, Bp3, 2, idx, fp32);
}

// ---------------- dual GEMM: both projections of a layer in one kernel ----------
// Block = 512 threads = 8 waves over rows [64b, 64b+64). Waves 0-3 -> (Bp0,C0),
// waves 4-7 -> (Bp1,C1); within a half, wave w4 owns n-tiles [6*w4, 6*w4+6) for
// all 4 m-tiles. A is read once per block into L1/L2 (second half hits cache) --
// halves A traffic vs two separate GEMMs. Barrier-free K-loop (r10-proven);
// in-place safe: pre-epilogue __syncthreads orders ALL A-reads before any store.
__global__ __launch_bounds__(512) void k_gemm_dual(const void* A_,
                       const unsigned short* __restrict__ Bp0,
                       const unsigned short* __restrict__ Bp1,
                       unsigned short* C0, unsigned short* C1, int K,
                       const int* __restrict__ flagp, int a_flagged) {
  int fp32 = a_flagged ? flagp[0] : 0;
  int tid  = threadIdx.x;
  int wave = tid >> 6, lane = tid & 63;
  int half = wave >> 2;
  int ntb  = (wave & 3) * 6;
  const unsigned short* Bp = half ? Bp1 : Bp0;
  unsigned short* C        = half ? C1  : C0;
  int m0   = blockIdx.x * 64;
  int lr   = lane & 15;
  int kk   = (lane >> 4) * 8;
  int rc[4];
#pragma unroll
  for (int mi = 0; mi < 4; ++mi) {
    int r = m0 + mi * 16 + lr;
    rc[mi] = r < N_NODES ? r : N_NODES - 1;
  }
  floatx4 acc[24];                       // [mi*6 + nt]
#pragma unroll
  for (int i = 0; i < 24; ++i) acc[i] = (floatx4){0.f, 0.f, 0.f, 0.f};
  int nk = K >> 5;
  for (int kt = 0; kt < nk; ++kt) {
    short8 af[4];
    if (fp32) {
#pragma unroll
      for (int mi = 0; mi < 4; ++mi) {
        const float* Af = (const float*)A_ + (size_t)rc[mi] * K + kt * 32 + kk;
        floatx4 f0 = *(const floatx4*)(Af);
        floatx4 f1 = *(const floatx4*)(Af + 4);
#pragma unroll
        for (int j = 0; j < 4; ++j) { af[mi][j] = (short)f2bf(f0[j]); af[mi][4 + j] = (short)f2bf(f1[j]); }
      }
    } else {
#pragma unroll
      for (int mi = 0; mi < 4; ++mi)
        af[mi] = *(const short8*)((const unsigned short*)A_ + (size_t)rc[mi] * K + kt * 32 + kk);
    }
    const short8* bp = (const short8*)Bp + ((size_t)kt * 24 + ntb) * 64 + lane;
#pragma unroll
    for (int nt = 0; nt < 6; ++nt) {
      short8 bf = bp[nt * 64];
      acc[0 * 6 + nt] = __builtin_amdgcn_mfma_f32_16x16x32_bf16(af[0], bf, acc[0 * 6 + nt], 0, 0, 0);
      acc[1 * 6 + nt] = __builtin_amdgcn_mfma_f32_16x16x32_bf16(af[1], bf, acc[1 * 6 + nt], 0, 0, 0);
      acc[2 * 6 + nt] = __builtin_amdgcn_mfma_f32_16x16x32_bf16(af[2], bf, acc[2 * 6 + nt], 0, 0, 0);
      acc[3 * 6 + nt] = __builtin_amdgcn_mfma_f32_16x16x32_bf16(af[3], bf, acc[3 * 6 + nt], 0, 0, 0);
    }
  }
  __syncthreads();                        // all A-loads complete before stores (in-place)
  int qr   = lane >> 4;
  int ccol = lane & 15;
#pragma unroll
  for (int mi = 0; mi < 4; ++mi)
#pragma unroll
    for (int nt = 0; nt < 6; ++nt)
#pragma unroll
      for (int r = 0; r < 4; ++r) {
        int orow = m0 + mi * 16 + qr * 4 + r;
        if (orow < N_NODES)
          C[(size_t)orow * HC + (ntb + nt) * 16 + ccol] = f2bf(fin(acc[mi * 6 + nt][r]));
      }
}

// ---------------- MLP-1 via MFMA: 4 waves/block, one 16-row tile each -----------
__global__ __launch_bounds__(256) void k_mlp1_mfma(const unsigned short* __restrict__ H2,
                            const unsigned short* __restrict__ Bp3,
                            const void* __restrict__ b3, float* __restrict__ H3,
                            const int* __restrict__ flagp) {
  int fp32 = flagp[0];
  int lane = threadIdx.x & 63;
  int tile = blockIdx.x * 4 + (threadIdx.x >> 6);
  int m0   = tile * 16;
  if (m0 >= N_NODES) return;
  int row  = m0 + (lane & 15);
  if (row >= N_NODES) row = N_NODES - 1;
  int kk   = (lane >> 4) * 8;
  floatx4 acc[2];
  acc[0] = (floatx4){0.f, 0.f, 0.f, 0.f};
  acc[1] = (floatx4){0.f, 0.f, 0.f, 0.f};
#pragma unroll
  for (int kt = 0; kt < 12; ++kt) {
    short8 af = *(const short8*)(H2 + (size_t)row * HC + kt * 32 + kk);
    const short8* bp = (const short8*)Bp3 + (size_t)kt * 2 * 64 + lane;
    acc[0] = __builtin_amdgcn_mfma_f32_16x16x32_bf16(af, bp[0],  acc[0], 0, 0, 0);
    acc[1] = __builtin_amdgcn_mfma_f32_16x16x32_bf16(af, bp[64], acc[1], 0, 0, 0);
  }
  int qr   = lane >> 4;
  int ccol = lane & 15;
#pragma unroll
  for (int nt = 0; nt < 2; ++nt)
#pragma unroll
    for (int r = 0; r < 4; ++r) {
      int col = nt * 16 + ccol;
      int orow = m0 + qr * 4 + r;
      if (orow < N_NODES) {
        float s = acc[nt][r] + fin(rdw(b3, col, fp32));
        s = s > 0.f ? s : expm1f(s);
        H3[(size_t)orow * 32 + col] = fin(s);
      }
    }
}

// ---------------- edge aggregation (r7 proven, FROZEN): wave per dst node -------
__global__ void k_edge(const unsigned short* __restrict__ XL, const unsigned short* XR,
                       const int* __restrict__ row_start, const int* __restrict__ csr_src,
                       const void* __restrict__ att, const void* __restrict__ bias,
                       unsigned short* H, const int* __restrict__ flagp) {
  int fp32 = flagp[0];
  int v = blockIdx.x;
  int L = threadIdx.x;
  float r0[3], r1[3], a0[3], a1[3];
  const uint* xr_row = (const uint*)(XR + (size_t)v * HC);
#pragma unroll
  for (int k = 0; k < 3; ++k) {
    uint rv = xr_row[L + 64 * k];
    r0[k] = bf2f((unsigned short)(rv & 0xFFFFu));
    r1[k] = bf2f((unsigned short)(rv >> 16));
    int c = 2 * L + 128 * k;
    a0[k] = fin(rdw(att, c, fp32));
    a1[k] = fin(rdw(att, c + 1, fp32));
  }
  float l[3]    = {0.f, 0.f, 0.f};
  float acc0[3] = {0.f, 0.f, 0.f};
  float acc1[3] = {0.f, 0.f, 0.f};
  int beg = row_start[v], end = row_start[v + 1];
  if (beg < 0) beg = 0;
  if (end > EN_TOT) end = EN_TOT;
  for (int e = beg; e < end; ++e) {
    int s = csr_src[e];
    if ((unsigned)s >= N_NODES) s = 0;
    const uint* xs = (const uint*)(XL + (size_t)s * HC);
    uint q[3];
    q[0] = xs[L];
    q[1] = xs[L + 64];
    q[2] = xs[L + 128];
#pragma unroll
    for (int k = 0; k < 3; ++k) {
      float s0 = bf2f((unsigned short)(q[k] & 0xFFFFu));
      float s1 = bf2f((unsigned short)(q[k] >> 16));
      float t0 = s0 + r0[k]; t0 = fmaxf(t0, 0.2f * t0);   // leaky_relu(t,0.2)
      float t1 = s1 + r1[k]; t1 = fmaxf(t1, 0.2f * t1);
      float w = t0 * a0[k] + t1 * a1[k];
      w += __shfl_xor(w, 1);
      w += __shfl_xor(w, 2);
      w += __shfl_xor(w, 4);
      w += __shfl_xor(w, 8);               // head logit, uniform in 16-lane group
      w = fminf(fmaxf(w, -87.f), 87.f);    // overflow hard-stop only
      float p = __expf(w);
      l[k] += p;
      acc0[k] = fmaf(p, s0, acc0[k]);
      acc1[k] = fmaf(p, s1, acc1[k]);
    }
  }
  uint* hr = (uint*)(H + (size_t)v * HC);
#pragma unroll
  for (int k = 0; k < 3; ++k) {
    int c = 2 * L + 128 * k;
    float inv = 1.f / fmaxf(l[k], 1e-30f);
    float o0 = acc0[k] * inv + fin(rdw(bias, c, fp32));
    float o1 = acc1[k] * inv + fin(rdw(bias, c + 1, fp32));
    o0 = o0 > 0.f ? o0 : expm1f(o0);
    o1 = o1 > 0.f ? o1 : expm1f(o1);
    hr[L + 64 * k] = (uint)f2bf(fin(o0)) | ((uint)f2bf(fin(o1)) << 16);
  }
}

// ---------------- MLP-2 + log_softmax: 4 nodes per 256-thread block -------------
__global__ __launch_bounds__(256) void k_mlp2(const float* __restrict__ H3,
                       const void* __restrict__ W4,
                       const void* __restrict__ b4, float* __restrict__ out,
                       const int* __restrict__ flagp) {
  int fp32 = flagp[0];
  int v = blockIdx.x * 4 + (threadIdx.x >> 6);
  if (v >= N_NODES) return;
  int L = threadIdx.x & 63;
  float logit = -1e30f;
  if (L < CLASSES) {
    logit = rdw(b4, L, fp32);
#pragma unroll
    for (int k = 0; k < 32; ++k)
      logit += H3[(size_t)v * 32 + k] * rdw(W4, k * CLASSES + L, fp32);
  }
  float mx = logit;
  for (int off = 1; off < 64; off <<= 1) mx = fmaxf(mx, __shfl_xor(mx, off));
  float ex = (L < CLASSES) ? __expf(logit - mx) : 0.f;
  ex = (ex == ex) ? ex : 0.f;
  float sm = ex;
  for (int off = 1; off < 64; off <<= 1) sm += __shfl_xor(sm, off);
  float ls = mx + logf(sm);
  if (L < CLASSES) out[(size_t)v * CLASSES + L] = fin(logit - ls);
}

extern "C" void kernel_launch(void* const* d_in, const int* in_sizes, int n_in,
                              void* d_out, int out_size, void* d_ws, size_t ws_size,
                              hipStream_t stream) {
  const void* x   = d_in[0];
  const int* ei   = (const int*)d_in[1];
  const void* Wl1 = d_in[2];
  const void* Wr1 = d_in[3];
  const void* a1  = d_in[4];
  const void* b1  = d_in[5];
  const void* Wl2 = d_in[6];
  const void* Wr2 = d_in[7];
  const void* a2  = d_in[8];
  const void* b2  = d_in[9];
  const void* W3  = d_in[10];
  const void* b3  = d_in[11];
  const void* W4  = d_in[12];
  const void* b4  = d_in[13];
  float* out = (float*)d_out;

  char* ws = (char*)d_ws;
  size_t off = 0;
  auto alloc = [&](size_t bytes) { size_t o = off; off += (bytes + 255) & ~(size_t)255; return o; };
  int* flag       = (int*)(ws + alloc(256));
  int* row_start  = (int*)(ws + alloc((size_t)(N_NODES + 1) * 4));
  int* cz         = (int*)(ws + alloc((size_t)2 * N_NODES * 4));   // counts+cursor contiguous
  int* counts     = cz;
  int* cursor     = cz + N_NODES;
  int* bsum       = (int*)(ws + alloc(64 * 4));
  int* csr_src    = (int*)(ws + alloc((size_t)EN_TOT * 4));
  unsigned short* Bp1l = (unsigned short*)(ws + alloc((size_t)SZ1 * 2));
  unsigned short* Bp1r = (unsigned short*)(ws + alloc((size_t)SZ1 * 2));
  unsigned short* Bp2l = (unsigned short*)(ws + alloc((size_t)SZ2 * 2));
  unsigned short* Bp2r = (unsigned short*)(ws + alloc((size_t)SZ2 * 2));
  unsigned short* Bp3  = (unsigned short*)(ws + alloc((size_t)SZ3 * 2));
  unsigned short* B0   = (unsigned short*)(ws + alloc((size_t)N_NODES * HC * 2));
  unsigned short* B1   = (unsigned short*)(ws + alloc((size_t)N_NODES * HC * 2));
  float* H3       = (float*)B0;  // reuses B0 after it's dead
  (void)in_sizes; (void)n_in;

  if (ws_size < off) {
    k_sentinel<<<(out_size + 255) / 256, 256, 0, stream>>>(out, out_size);
    return;
  }

  const int SCAN_BLOCKS = (N_NODES + 1023) / 1024;   // 49
  const int GEMM_BLOCKS = (N_NODES + 63) / 64;       // 782

  k_detect<<<1, 64, 0, stream>>>((const unsigned short*)x, flag);

  // --- CSR by dst ---
  k_zero2<<<(2 * N_NODES + 255) / 256, 256, 0, stream>>>(cz, 2 * N_NODES);
  k_count<<<(EN_TOT + 255) / 256, 256, 0, stream>>>(ei, counts);
  k_scan1<<<SCAN_BLOCKS, 1024, 0, stream>>>(counts, row_start, bsum);
  k_scan2<<<1, 64, 0, stream>>>(bsum, SCAN_BLOCKS);
  k_scan3<<<SCAN_BLOCKS, 1024, 0, stream>>>(row_start, bsum);
  k_fill<<<(EN_TOT + 255) / 256, 256, 0, stream>>>(ei, row_start, cursor, csr_src);

  // --- pack all weights once ---
  k_pack_all<<<(SZALL + 255) / 256, 256, 0, stream>>>(Wl1, Wr1, Wl2, Wr2, W3,
                                                      Bp1l, Bp1r, Bp2l, Bp2r, Bp3, flag);

  // --- layer 1: xl,xr in one dual GEMM ---
  k_gemm_dual<<<GEMM_BLOCKS, 512, 0, stream>>>(x, Bp1l, Bp1r, B0, B1, F_IN, flag, 1);
  k_edge<<<N_NODES, 64, 0, stream>>>(B0, B1, row_start, csr_src, a1, b1, B1, flag);

  // --- layer 2: xl2 -> B0, xr2 -> B1 (in-place) in one dual GEMM ---
  k_gemm_dual<<<GEMM_BLOCKS, 512, 0, stream>>>(B1, Bp2l, Bp2r, B0, B1, HC, flag, 0);
  k_edge<<<N_NODES, 64, 0, stream>>>(B0, B1, row_start, csr_src, a2, b2, B1, flag);

  // --- MLP head + log_softmax ---
  k_mlp1_mfma<<<(N_NODES / 16 + 3) / 4, 256, 0, stream>>>(B1, Bp3, b3, H3, flag);
  k_mlp2<<<(N_NODES + 3) / 4, 256, 0, stream>>>(H3, W4, b4, out, flag);
}